// Round 9
// baseline (702.444 us; speedup 1.0000x reference)
//
#include <hip/hip_runtime.h>
#include <math.h>

// ---------------------------------------------------------------------------
// CDAttnBlock round 9:
//   attn: P hi/lo stores merged to uint2 (b64 floor, conflict-free);
//         defer-max rescale (T13, THR=8).
//   gemms: 2-phase prefetch (double-buffered LDS, stage k+1 before compute k,
//          one barrier per K-tile) on gemm_qkv + gemm_out.
// Everything else unchanged from validated round 8.
// ---------------------------------------------------------------------------

#define HIDDEN 768
#define NH 12
#define HD 64
#define BB 8
#define SS 1024
#define ATT_SCALE 0.125f

typedef unsigned short u16;
typedef unsigned int u32;
typedef __attribute__((ext_vector_type(8))) short short8;   // 8 bf16
typedef __attribute__((ext_vector_type(4))) float f32x4;

constexpr int MROWS = BB * SS;            // 8192
constexpr int M_QKV = 2 * MROWS;          // 16384
constexpr int N_QKV = 3 * HIDDEN;         // 2304
constexpr long QKV_ELEMS = (long)BB * NH * SS * HD;    // 6,291,456
constexpr long AX_ELEMS  = (long)M_QKV * HIDDEN;       // 12,582,912
constexpr long O_ELEMS   = (long)3 * MROWS * HIDDEN;   // 18,874,368
constexpr long WQT_ELEMS = (long)N_QKV * HIDDEN;       // 1,769,472
constexpr size_t OFF2 = (size_t)12 * QKV_ELEMS * 2;    // 150,994,944 B

__device__ inline u16 f2bf(float x) {     // fp32 -> bf16 RTN
    u32 u = __float_as_uint(x);
    return (u16)((u + 0x7FFFu + ((u >> 16) & 1u)) >> 16);
}
__device__ inline float bf2f(u16 h) { return __uint_as_float(((u32)h) << 16); }
__device__ inline int swz(int row, int bcol) {      // K/P swizzle (G4)
    return ((row << 7) + bcol) ^ ((row & 7) << 4);
}
// Vt swizzle: transpose-write lanes (rows = i mod 8) spread over 8 slots.
__device__ inline int swzV(int row, int bcol) {
    return ((row << 7) + bcol) ^ ((((row >> 3) ^ row) & 7) << 4);
}
#define MFMA16(a, b, c) __builtin_amdgcn_mfma_f32_16x16x32_bf16(a, b, c, 0, 0, 0)

__device__ inline void gload16(const u16* g, u16* l) {
    __builtin_amdgcn_global_load_lds(
        (const __attribute__((address_space(1))) u32*)g,
        (__attribute__((address_space(3))) u32*)l, 16, 0, 0);
}

// ---------------------------------------------------------------------------
// k0: x, x2 -> Ax hi/lo planes (elementwise, vectorized)
// ---------------------------------------------------------------------------
__global__ __launch_bounds__(256) void conv_x_kernel(
    const float* __restrict__ x, const float* __restrict__ x2,
    u16* __restrict__ axh, u16* __restrict__ axl)
{
    const size_t HALF = (size_t)MROWS * HIDDEN;
    const size_t NTOT = (size_t)AX_ELEMS;
    const size_t step = (size_t)gridDim.x * 256 * 4;
    for (size_t e = ((size_t)blockIdx.x * 256 + threadIdx.x) * 4; e < NTOT; e += step) {
        const float4 v = (e < HALF) ? *(const float4*)&x[e]
                                    : *(const float4*)&x2[e - HALF];
        ushort4 h, l;
        h.x = f2bf(v.x); l.x = f2bf(v.x - bf2f(h.x));
        h.y = f2bf(v.y); l.y = f2bf(v.y - bf2f(h.y));
        h.z = f2bf(v.z); l.z = f2bf(v.z - bf2f(h.z));
        h.w = f2bf(v.w); l.w = f2bf(v.w - bf2f(h.w));
        *(ushort4*)&axh[e] = h;
        *(ushort4*)&axl[e] = l;
    }
}

// ---------------------------------------------------------------------------
// k1: weight transposes -> hi/lo planes (unchanged)
// ---------------------------------------------------------------------------
__global__ __launch_bounds__(256) void conv_wt_kernel(
    const float* __restrict__ Wqkv, const float* __restrict__ Wout,
    u16* __restrict__ wqt_h, u16* __restrict__ wqt_l,
    u16* __restrict__ wot_h, u16* __restrict__ wot_l)
{
    __shared__ float T[64][65];
    const int bk = blockIdx.x;
    int bn = blockIdx.y;
    const float* W; int ncols; u16 *oh, *ol;
    if (bn < 36) { W = Wqkv; ncols = N_QKV; oh = wqt_h; ol = wqt_l; }
    else         { W = Wout; ncols = HIDDEN; oh = wot_h; ol = wot_l; bn -= 36; }
    const int k0 = bk * 64, n0 = bn * 64;
    const int t = threadIdx.x;
    {
        const int r = t >> 2, c0 = (t & 3) * 16;
        #pragma unroll
        for (int q = 0; q < 4; ++q) {
            const float4 v = *(const float4*)&W[(size_t)(k0 + r) * ncols + n0 + c0 + q * 4];
            T[r][c0 + q * 4 + 0] = v.x;
            T[r][c0 + q * 4 + 1] = v.y;
            T[r][c0 + q * 4 + 2] = v.z;
            T[r][c0 + q * 4 + 3] = v.w;
        }
    }
    __syncthreads();
    {
        const int n = t >> 2, kk0 = (t & 3) * 16;
        const size_t ob = (size_t)(n0 + n) * HIDDEN + k0 + kk0;
        #pragma unroll
        for (int q = 0; q < 4; ++q) {
            ushort4 h, l;
            float v0 = T[kk0 + q * 4 + 0][n];
            float v1 = T[kk0 + q * 4 + 1][n];
            float v2 = T[kk0 + q * 4 + 2][n];
            float v3 = T[kk0 + q * 4 + 3][n];
            h.x = f2bf(v0); l.x = f2bf(v0 - bf2f(h.x));
            h.y = f2bf(v1); l.y = f2bf(v1 - bf2f(h.y));
            h.z = f2bf(v2); l.z = f2bf(v2 - bf2f(h.z));
            h.w = f2bf(v3); l.w = f2bf(v3 - bf2f(h.w));
            *(ushort4*)&oh[ob + q * 4] = h;
            *(ushort4*)&ol[ob + q * 4] = l;
        }
    }
}

// ---------------------------------------------------------------------------
// k2: MFMA GEMM qkv, 2-phase prefetch (stage k+1 while computing k).
// ---------------------------------------------------------------------------
__global__ __launch_bounds__(256)
__attribute__((amdgpu_waves_per_eu(2, 2)))
void gemm_qkv_mfma(const u16* __restrict__ Agh, const u16* __restrict__ Agl,
                   const u16* __restrict__ Bgh, const u16* __restrict__ Bgl,
                   u16* __restrict__ planes)
{
    __shared__ u16 LAh[2][4096], LAl[2][4096], LBh[2][4096], LBl[2][4096]; // 64KB

    const int tid = threadIdx.x, lane = tid & 63, wid = tid >> 6;
    const int l15 = lane & 15, lg = lane >> 4;
    const int wr = wid >> 1, wc = wid & 1;
    const int m0 = blockIdx.x * 128, n0 = blockIdx.y * 128;

    auto stage = [&](int kt, int bf) {
        const int k0 = kt * 32;
        #pragma unroll
        for (int u = 0; u < 2; ++u) {
            const int s   = (wid * 2 + u) * 64 + lane;
            const int row = s >> 2;
            const int kc  = (s & 3) * 8;
            const int lo  = (wid * 2 + u) * 512;
            const size_t ga = (size_t)(m0 + row) * HIDDEN + k0 + kc;
            const size_t gb = (size_t)(n0 + row) * HIDDEN + k0 + kc;
            gload16(Agh + ga, &LAh[bf][lo]);
            gload16(Agl + ga, &LAl[bf][lo]);
            gload16(Bgh + gb, &LBh[bf][lo]);
            gload16(Bgl + gb, &LBl[bf][lo]);
        }
    };

    const f32x4 fz = {0.f, 0.f, 0.f, 0.f};
    f32x4 acc[4][4] = {{fz,fz,fz,fz},{fz,fz,fz,fz},{fz,fz,fz,fz},{fz,fz,fz,fz}};

    stage(0, 0);
    __syncthreads();                       // drain prologue loads

    int bf = 0;
    for (int kt = 0; kt < HIDDEN / 32; ++kt) {
        if (kt + 1 < HIDDEN / 32) stage(kt + 1, bf ^ 1);   // prefetch next

        short8 ah[4], al[4], bh[4], bl[4];
        #pragma unroll
        for (int i = 0; i < 4; ++i) {
            const int ro = (wr * 64 + i * 16 + l15) * 32 + lg * 8;
            ah[i] = *(const short8*)&LAh[bf][ro];
            al[i] = *(const short8*)&LAl[bf][ro];
        }
        #pragma unroll
        for (int j = 0; j < 4; ++j) {
            const int ro = (wc * 64 + j * 16 + l15) * 32 + lg * 8;
            bh[j] = *(const short8*)&LBh[bf][ro];
            bl[j] = *(const short8*)&LBl[bf][ro];
        }
        #pragma unroll
        for (int i = 0; i < 4; ++i)
            #pragma unroll
            for (int j = 0; j < 4; ++j) {
                acc[i][j] = MFMA16(ah[i], bh[j], acc[i][j]);
                acc[i][j] = MFMA16(ah[i], bl[j], acc[i][j]);
                acc[i][j] = MFMA16(al[i], bh[j], acc[i][j]);
            }
        __syncthreads();                   // next-tile loads drained; bufs safe
        bf ^= 1;
    }

    #pragma unroll
    for (int i = 0; i < 4; ++i) {
        #pragma unroll
        for (int r = 0; r < 4; ++r) {
            const int mr  = m0 + wr * 64 + i * 16 + lg * 4 + r;
            const int inp = (mr >= MROWS) ? 1 : 0;
            const int mm  = mr & (MROWS - 1);
            const int bb  = mm >> 10, ssr = mm & (SS - 1);
            #pragma unroll
            for (int j = 0; j < 4; ++j) {
                const int n   = n0 + wc * 64 + j * 16 + l15;
                const int sel = n / HIDDEN;
                const int hh  = (n % HIDDEN) >> 6;
                const int dd  = n & 63;
                const float v = acc[i][j][r];
                const u16 vh = f2bf(v);
                const u16 vl = f2bf(v - bf2f(vh));
                u16* ph = planes + (size_t)(inp * 6 + sel * 2) * QKV_ELEMS;
                const size_t idx = (((size_t)bb * NH + hh) * SS + ssr) * HD + dd;
                ph[idx] = vh;
                ph[QKV_ELEMS + idx] = vl;
            }
        }
    }
}

// ---------------------------------------------------------------------------
// k3: MFMA flash attention (round-8 structure + uint2 P-stores + defer-max)
// ---------------------------------------------------------------------------
__global__ __launch_bounds__(256)
__attribute__((amdgpu_waves_per_eu(2, 2)))
void attn_mfma_kernel(const u16* __restrict__ planes,
                      u16* __restrict__ o_h, u16* __restrict__ o_l)
{
    __shared__ u16 Khi[64 * 64], Klo[64 * 64];     // [key][d]   8 KB each
    __shared__ u16 Vthi[64 * 64], Vtlo[64 * 64];   // [d][key]   8 KB each
    __shared__ u16 Pbuf[4][2][2][16 * 64];         // [wave][grp][hi/lo] 32 KB

    const int tid  = threadIdx.x;
    const int lane = tid & 63, wid = tid >> 6;
    const int l15  = lane & 15, lg = lane >> 4;

    // XCD-aware bijective swizzle (validated round 8)
    const int work = (blockIdx.x & 7) * 288 + (blockIdx.x >> 3);
    const int qt   = work & 7;
    const int bh   = (work >> 3) % 96;
    const int aid  = (work >> 3) / 96;

    const int qinp  = (aid == 1) ? 1 : 0;
    const int kvinp = (aid == 0) ? 0 : 1;
    const size_t base = (size_t)bh * SS * HD;

    const u16* __restrict__ qhi = planes + (size_t)(qinp * 6 + 0) * QKV_ELEMS;
    const u16* __restrict__ qlo = qhi + QKV_ELEMS;
    const u16* __restrict__ khi = planes + (size_t)(kvinp * 6 + 2) * QKV_ELEMS;
    const u16* __restrict__ klo = khi + QKV_ELEMS;
    const u16* __restrict__ vhi = planes + (size_t)(kvinp * 6 + 4) * QKV_ELEMS;
    const u16* __restrict__ vlo = vhi + QKV_ELEMS;

    const int qb = qt * 128 + wid * 32;
    short8 qfh[2][2], qfl[2][2];                   // [group][dk]
    #pragma unroll
    for (int g = 0; g < 2; ++g)
        #pragma unroll
        for (int dk = 0; dk < 2; ++dk) {
            const size_t off = base + (size_t)(qb + g * 16 + l15) * HD + dk * 32 + lg * 8;
            qfh[g][dk] = *(const short8*)&qhi[off];
            qfl[g][dk] = *(const short8*)&qlo[off];
        }

    const f32x4 fz = {0.f, 0.f, 0.f, 0.f};
    f32x4 O[2][4] = {{fz, fz, fz, fz}, {fz, fz, fz, fz}};
    float mrun[2] = {-INFINITY, -INFINITY};
    float lrun[2] = {0.f, 0.f};

    for (int kt0 = 0; kt0 < SS; kt0 += 64) {
        __syncthreads();
        {   // ---- stage K (swz) and V transposed (swzV) ----
            #pragma unroll
            for (int i = 0; i < 2; ++i) {
                const int c  = tid + 256 * i;
                const int ky = c >> 3, dg = (c & 7) * 8;
                const size_t g = base + (size_t)(kt0 + ky) * HD + dg;
                const int b = swz(ky, dg * 2);
                *(short8*)((char*)Khi + b) = *(const short8*)&khi[g];
                *(short8*)((char*)Klo + b) = *(const short8*)&klo[g];
            }
            const int kp = tid >> 3;
            const int d0 = (tid & 7) * 8;
            const size_t g0 = base + (size_t)(kt0 + 2 * kp) * HD + d0;
            short8 vah = *(const short8*)&vhi[g0];
            short8 vbh = *(const short8*)&vhi[g0 + HD];
            short8 val = *(const short8*)&vlo[g0];
            short8 vbl = *(const short8*)&vlo[g0 + HD];
            #pragma unroll
            for (int i = 0; i < 8; ++i) {
                const int d = d0 + i;
                const int b = swzV(d, kp * 4);
                *(u32*)((char*)Vthi + b) = (u32)(u16)vah[i] | ((u32)(u16)vbh[i] << 16);
                *(u32*)((char*)Vtlo + b) = (u32)(u16)val[i] | ((u32)(u16)vbl[i] << 16);
            }
        }
        __syncthreads();

        // ---- S^T = K Q ----
        f32x4 S[2][4] = {{fz, fz, fz, fz}, {fz, fz, fz, fz}};
        #pragma unroll
        for (int dk = 0; dk < 2; ++dk) {
            #pragma unroll
            for (int kt = 0; kt < 4; ++kt) {
                const int b = swz(kt * 16 + l15, dk * 64 + lg * 16);
                short8 kfh = *(const short8*)((char*)Khi + b);
                short8 kfl = *(const short8*)((char*)Klo + b);
                #pragma unroll
                for (int g = 0; g < 2; ++g) {
                    S[g][kt] = MFMA16(kfh, qfh[g][dk], S[g][kt]);
                    S[g][kt] = MFMA16(kfl, qfh[g][dk], S[g][kt]);
                    S[g][kt] = MFMA16(kfh, qfl[g][dk], S[g][kt]);
                }
            }
        }

        // ---- per-group softmax (defer-max, THR=8) ----
        #pragma unroll
        for (int g = 0; g < 2; ++g) {
            float pm = -INFINITY;
            #pragma unroll
            for (int kt = 0; kt < 4; ++kt)
                #pragma unroll
                for (int r = 0; r < 4; ++r) {
                    S[g][kt][r] *= ATT_SCALE;
                    pm = fmaxf(pm, S[g][kt][r]);
                }
            pm = fmaxf(pm, __shfl_xor(pm, 16, 64));
            pm = fmaxf(pm, __shfl_xor(pm, 32, 64));

            if (__any(pm - mrun[g] > 8.f)) {       // wave-uniform rescale
                const float mnew = fmaxf(mrun[g], pm);
                const float corr = __expf(mrun[g] - mnew);
                lrun[g] *= corr;
                #pragma unroll
                for (int r = 0; r < 4; ++r) {
                    const float c = __shfl(corr, lg * 4 + r, 64);
                    #pragma unroll
                    for (int dn = 0; dn < 4; ++dn) O[g][dn][r] *= c;
                }
                mrun[g] = mnew;
            }
            const float mref = mrun[g];

            u16* __restrict__ Ph = &Pbuf[wid][g][0][0];
            u16* __restrict__ Pl = &Pbuf[wid][g][1][0];
            float psum = 0.f;
            #pragma unroll
            for (int kt = 0; kt < 4; ++kt) {
                float p0 = __expf(S[g][kt][0] - mref);
                float p1 = __expf(S[g][kt][1] - mref);
                float p2 = __expf(S[g][kt][2] - mref);
                float p3 = __expf(S[g][kt][3] - mref);
                psum += (p0 + p1) + (p2 + p3);
                const u32 u0 = __float_as_uint(p0), u1 = __float_as_uint(p1);
                const u32 u2 = __float_as_uint(p2), u3 = __float_as_uint(p3);
                const u32 hpk0 = (u0 >> 16) | (u1 & 0xFFFF0000u);
                const u32 hpk1 = (u2 >> 16) | (u3 & 0xFFFF0000u);
                const float l0 = p0 - __uint_as_float(u0 & 0xFFFF0000u);
                const float l1 = p1 - __uint_as_float(u1 & 0xFFFF0000u);
                const float l2 = p2 - __uint_as_float(u2 & 0xFFFF0000u);
                const float l3 = p3 - __uint_as_float(u3 & 0xFFFF0000u);
                const u32 lpk0 = (__float_as_uint(l0) >> 16) | (__float_as_uint(l1) & 0xFFFF0000u);
                const u32 lpk1 = (__float_as_uint(l2) >> 16) | (__float_as_uint(l3) & 0xFFFF0000u);
                const int b0 = swz(l15, kt * 32 + lg * 8);
                *(uint2*)((char*)Ph + b0) = make_uint2(hpk0, hpk1);  // b64, CF
                *(uint2*)((char*)Pl + b0) = make_uint2(lpk0, lpk1);
            }
            psum += __shfl_xor(psum, 16, 64);
            psum += __shfl_xor(psum, 32, 64);
            lrun[g] += psum;
        }

        // ---- O += P V ----
        #pragma unroll
        for (int ch = 0; ch < 2; ++ch) {
            short8 vfh[4], vfl[4];
            #pragma unroll
            for (int dn = 0; dn < 4; ++dn) {
                const int vb = swzV(dn * 16 + l15, ch * 64 + lg * 16);
                vfh[dn] = *(const short8*)((char*)Vthi + vb);
                vfl[dn] = *(const short8*)((char*)Vtlo + vb);
            }
            #pragma unroll
            for (int g = 0; g < 2; ++g) {
                const int pb = swz(l15, ch * 64 + lg * 16);
                short8 pah = *(const short8*)((char*)&Pbuf[wid][g][0][0] + pb);
                short8 pal = *(const short8*)((char*)&Pbuf[wid][g][1][0] + pb);
                #pragma unroll
                for (int dn = 0; dn < 4; ++dn) {
                    O[g][dn] = MFMA16(pah, vfh[dn], O[g][dn]);
                    O[g][dn] = MFMA16(pah, vfl[dn], O[g][dn]);
                    O[g][dn] = MFMA16(pal, vfh[dn], O[g][dn]);
                }
            }
        }
    }

    // ---- epilogue ----
    const int b = bh / NH, h = bh % NH;
    #pragma unroll
    for (int g = 0; g < 2; ++g) {
        const float linv = 1.f / lrun[g];
        #pragma unroll
        for (int r = 0; r < 4; ++r) {
            const float inv = __shfl(linv, lg * 4 + r, 64);
            const int grow = aid * MROWS + b * SS + qb + g * 16 + lg * 4 + r;
            const size_t rb = (size_t)grow * HIDDEN + h * HD;
            #pragma unroll
            for (int dn = 0; dn < 4; ++dn) {
                const float v = O[g][dn][r] * inv;
                const u16 vh = f2bf(v);
                o_h[rb + dn * 16 + l15] = vh;
                o_l[rb + dn * 16 + l15] = f2bf(v - bf2f(vh));
            }
        }
    }
}

// ---------------------------------------------------------------------------
// k4: MFMA GEMM out, 2-phase prefetch
// ---------------------------------------------------------------------------
__global__ __launch_bounds__(256)
__attribute__((amdgpu_waves_per_eu(2, 2)))
void gemm_out_mfma(const u16* __restrict__ Agh, const u16* __restrict__ Agl,
                   const u16* __restrict__ Bgh, const u16* __restrict__ Bgl,
                   const float* __restrict__ bias, float* __restrict__ out)
{
    __shared__ u16 LAh[2][4096], LAl[2][4096], LBh[2][4096], LBl[2][4096];

    const int tid = threadIdx.x, lane = tid & 63, wid = tid >> 6;
    const int l15 = lane & 15, lg = lane >> 4;
    const int wr = wid >> 1, wc = wid & 1;
    const int m0 = blockIdx.x * 128, n0 = blockIdx.y * 128;

    auto stage = [&](int kt, int bf) {
        const int k0 = kt * 32;
        #pragma unroll
        for (int u = 0; u < 2; ++u) {
            const int s   = (wid * 2 + u) * 64 + lane;
            const int row = s >> 2;
            const int kc  = (s & 3) * 8;
            const int lo  = (wid * 2 + u) * 512;
            const size_t ga = (size_t)(m0 + row) * HIDDEN + k0 + kc;
            const size_t gb = (size_t)(n0 + row) * HIDDEN + k0 + kc;
            gload16(Agh + ga, &LAh[bf][lo]);
            gload16(Agl + ga, &LAl[bf][lo]);
            gload16(Bgh + gb, &LBh[bf][lo]);
            gload16(Bgl + gb, &LBl[bf][lo]);
        }
    };

    const f32x4 fz = {0.f, 0.f, 0.f, 0.f};
    f32x4 acc[4][4] = {{fz,fz,fz,fz},{fz,fz,fz,fz},{fz,fz,fz,fz},{fz,fz,fz,fz}};

    stage(0, 0);
    __syncthreads();

    int bf = 0;
    for (int kt = 0; kt < HIDDEN / 32; ++kt) {
        if (kt + 1 < HIDDEN / 32) stage(kt + 1, bf ^ 1);

        short8 ah[4], al[4], bh[4], bl[4];
        #pragma unroll
        for (int i = 0; i < 4; ++i) {
            const int ro = (wr * 64 + i * 16 + l15) * 32 + lg * 8;
            ah[i] = *(const short8*)&LAh[bf][ro];
            al[i] = *(const short8*)&LAl[bf][ro];
        }
        #pragma unroll
        for (int j = 0; j < 4; ++j) {
            const int ro = (wc * 64 + j * 16 + l15) * 32 + lg * 8;
            bh[j] = *(const short8*)&LBh[bf][ro];
            bl[j] = *(const short8*)&LBl[bf][ro];
        }
        #pragma unroll
        for (int i = 0; i < 4; ++i)
            #pragma unroll
            for (int j = 0; j < 4; ++j) {
                acc[i][j] = MFMA16(ah[i], bh[j], acc[i][j]);
                acc[i][j] = MFMA16(ah[i], bl[j], acc[i][j]);
                acc[i][j] = MFMA16(al[i], bh[j], acc[i][j]);
            }
        __syncthreads();
        bf ^= 1;
    }

    #pragma unroll
    for (int i = 0; i < 4; ++i) {
        #pragma unroll
        for (int r = 0; r < 4; ++r) {
            const int mr = m0 + wr * 64 + i * 16 + lg * 4 + r;
            #pragma unroll
            for (int j = 0; j < 4; ++j) {
                const int n = n0 + wc * 64 + j * 16 + l15;
                out[(size_t)mr * HIDDEN + n] = acc[i][j][r] + bias[n];
            }
        }
    }
}

// ---------------------------------------------------------------------------
extern "C" void kernel_launch(void* const* d_in, const int* in_sizes, int n_in,
                              void* d_out, int out_size, void* d_ws, size_t ws_size,
                              hipStream_t stream)
{
    const float* x    = (const float*)d_in[0];
    const float* x2   = (const float*)d_in[1];
    const float* Wqkv = (const float*)d_in[2];
    const float* Wout = (const float*)d_in[3];
    const float* bout = (const float*)d_in[4];
    float* out = (float*)d_out;

    char* wsb = (char*)d_ws;
    u16* planes = (u16*)wsb;
    u16* ax_h  = (u16*)(wsb + OFF2);
    u16* ax_l  = ax_h + AX_ELEMS;
    u16* wqt_h = ax_l + AX_ELEMS;
    u16* wqt_l = wqt_h + WQT_ELEMS;
    u16* o_h   = (u16*)(wsb + OFF2);
    u16* o_l   = o_h + O_ELEMS;
    u16* wot_h = o_l + O_ELEMS;
    u16* wot_l = wot_h + (long)HIDDEN * HIDDEN;

    conv_x_kernel<<<3072, 256, 0, stream>>>(x, x2, ax_h, ax_l);

    dim3 gw(12, 48);
    conv_wt_kernel<<<gw, 256, 0, stream>>>(Wqkv, Wout, wqt_h, wqt_l, wot_h, wot_l);

    dim3 g1(M_QKV / 128, N_QKV / 128);            // 128 x 18
    gemm_qkv_mfma<<<g1, 256, 0, stream>>>(ax_h, ax_l, wqt_h, wqt_l, planes);

    attn_mfma_kernel<<<2304, 256, 0, stream>>>(planes, o_h, o_l);

    dim3 g3(3 * MROWS / 128, HIDDEN / 128);       // 192 x 6
    gemm_out_mfma<<<g3, 256, 0, stream>>>(o_h, o_l, wot_h, wot_l, bout, out);
}

// Round 10
// 659.291 us; speedup vs baseline: 1.0655x; 1.0655x over previous
//
#include <hip/hip_runtime.h>
#include <math.h>

// ---------------------------------------------------------------------------
// CDAttnBlock round 10:
//   gemms: REVERT to round-8 single-buffer 2-barrier loop (r9's 64KB dbuf cut
//          blocks/CU 3->2 and regressed); one delta: waves_per_eu(2,3) so the
//          allocator may co-resident 3 blocks/CU (m114 cross-block overlap).
//   attn:  unchanged round-9 (defer-max + uint2 P-stores, 291 us validated).
// ---------------------------------------------------------------------------

#define HIDDEN 768
#define NH 12
#define HD 64
#define BB 8
#define SS 1024
#define ATT_SCALE 0.125f

typedef unsigned short u16;
typedef unsigned int u32;
typedef __attribute__((ext_vector_type(8))) short short8;   // 8 bf16
typedef __attribute__((ext_vector_type(4))) float f32x4;

constexpr int MROWS = BB * SS;            // 8192
constexpr int M_QKV = 2 * MROWS;          // 16384
constexpr int N_QKV = 3 * HIDDEN;         // 2304
constexpr long QKV_ELEMS = (long)BB * NH * SS * HD;    // 6,291,456
constexpr long AX_ELEMS  = (long)M_QKV * HIDDEN;       // 12,582,912
constexpr long O_ELEMS   = (long)3 * MROWS * HIDDEN;   // 18,874,368
constexpr long WQT_ELEMS = (long)N_QKV * HIDDEN;       // 1,769,472
constexpr size_t OFF2 = (size_t)12 * QKV_ELEMS * 2;    // 150,994,944 B

__device__ inline u16 f2bf(float x) {     // fp32 -> bf16 RTN
    u32 u = __float_as_uint(x);
    return (u16)((u + 0x7FFFu + ((u >> 16) & 1u)) >> 16);
}
__device__ inline float bf2f(u16 h) { return __uint_as_float(((u32)h) << 16); }
__device__ inline int swz(int row, int bcol) {      // K/P swizzle (G4)
    return ((row << 7) + bcol) ^ ((row & 7) << 4);
}
// Vt swizzle: transpose-write lanes (rows = i mod 8) spread over 8 slots.
__device__ inline int swzV(int row, int bcol) {
    return ((row << 7) + bcol) ^ ((((row >> 3) ^ row) & 7) << 4);
}
#define MFMA16(a, b, c) __builtin_amdgcn_mfma_f32_16x16x32_bf16(a, b, c, 0, 0, 0)

__device__ inline void gload16(const u16* g, u16* l) {
    __builtin_amdgcn_global_load_lds(
        (const __attribute__((address_space(1))) u32*)g,
        (__attribute__((address_space(3))) u32*)l, 16, 0, 0);
}

// ---------------------------------------------------------------------------
// k0: x, x2 -> Ax hi/lo planes (elementwise, vectorized)
// ---------------------------------------------------------------------------
__global__ __launch_bounds__(256) void conv_x_kernel(
    const float* __restrict__ x, const float* __restrict__ x2,
    u16* __restrict__ axh, u16* __restrict__ axl)
{
    const size_t HALF = (size_t)MROWS * HIDDEN;
    const size_t NTOT = (size_t)AX_ELEMS;
    const size_t step = (size_t)gridDim.x * 256 * 4;
    for (size_t e = ((size_t)blockIdx.x * 256 + threadIdx.x) * 4; e < NTOT; e += step) {
        const float4 v = (e < HALF) ? *(const float4*)&x[e]
                                    : *(const float4*)&x2[e - HALF];
        ushort4 h, l;
        h.x = f2bf(v.x); l.x = f2bf(v.x - bf2f(h.x));
        h.y = f2bf(v.y); l.y = f2bf(v.y - bf2f(h.y));
        h.z = f2bf(v.z); l.z = f2bf(v.z - bf2f(h.z));
        h.w = f2bf(v.w); l.w = f2bf(v.w - bf2f(h.w));
        *(ushort4*)&axh[e] = h;
        *(ushort4*)&axl[e] = l;
    }
}

// ---------------------------------------------------------------------------
// k1: weight transposes -> hi/lo planes (unchanged)
// ---------------------------------------------------------------------------
__global__ __launch_bounds__(256) void conv_wt_kernel(
    const float* __restrict__ Wqkv, const float* __restrict__ Wout,
    u16* __restrict__ wqt_h, u16* __restrict__ wqt_l,
    u16* __restrict__ wot_h, u16* __restrict__ wot_l)
{
    __shared__ float T[64][65];
    const int bk = blockIdx.x;
    int bn = blockIdx.y;
    const float* W; int ncols; u16 *oh, *ol;
    if (bn < 36) { W = Wqkv; ncols = N_QKV; oh = wqt_h; ol = wqt_l; }
    else         { W = Wout; ncols = HIDDEN; oh = wot_h; ol = wot_l; bn -= 36; }
    const int k0 = bk * 64, n0 = bn * 64;
    const int t = threadIdx.x;
    {
        const int r = t >> 2, c0 = (t & 3) * 16;
        #pragma unroll
        for (int q = 0; q < 4; ++q) {
            const float4 v = *(const float4*)&W[(size_t)(k0 + r) * ncols + n0 + c0 + q * 4];
            T[r][c0 + q * 4 + 0] = v.x;
            T[r][c0 + q * 4 + 1] = v.y;
            T[r][c0 + q * 4 + 2] = v.z;
            T[r][c0 + q * 4 + 3] = v.w;
        }
    }
    __syncthreads();
    {
        const int n = t >> 2, kk0 = (t & 3) * 16;
        const size_t ob = (size_t)(n0 + n) * HIDDEN + k0 + kk0;
        #pragma unroll
        for (int q = 0; q < 4; ++q) {
            ushort4 h, l;
            float v0 = T[kk0 + q * 4 + 0][n];
            float v1 = T[kk0 + q * 4 + 1][n];
            float v2 = T[kk0 + q * 4 + 2][n];
            float v3 = T[kk0 + q * 4 + 3][n];
            h.x = f2bf(v0); l.x = f2bf(v0 - bf2f(h.x));
            h.y = f2bf(v1); l.y = f2bf(v1 - bf2f(h.y));
            h.z = f2bf(v2); l.z = f2bf(v2 - bf2f(h.z));
            h.w = f2bf(v3); l.w = f2bf(v3 - bf2f(h.w));
            *(ushort4*)&oh[ob + q * 4] = h;
            *(ushort4*)&ol[ob + q * 4] = l;
        }
    }
}

// ---------------------------------------------------------------------------
// k2: MFMA GEMM qkv, single-buffer 2-barrier loop (round-8 validated body;
// waves_per_eu(2,3) is the only delta -> up to 3 blocks/CU)
// ---------------------------------------------------------------------------
__global__ __launch_bounds__(256)
__attribute__((amdgpu_waves_per_eu(2, 3)))
void gemm_qkv_mfma(const u16* __restrict__ Agh, const u16* __restrict__ Agl,
                   const u16* __restrict__ Bgh, const u16* __restrict__ Bgl,
                   u16* __restrict__ planes)
{
    __shared__ u16 LAh[4096], LAl[4096], LBh[4096], LBl[4096];  // 32 KB

    const int tid = threadIdx.x, lane = tid & 63, wid = tid >> 6;
    const int l15 = lane & 15, lg = lane >> 4;
    const int wr = wid >> 1, wc = wid & 1;
    const int m0 = blockIdx.x * 128, n0 = blockIdx.y * 128;

    const f32x4 fz = {0.f, 0.f, 0.f, 0.f};
    f32x4 acc[4][4] = {{fz,fz,fz,fz},{fz,fz,fz,fz},{fz,fz,fz,fz},{fz,fz,fz,fz}};

    for (int kt = 0; kt < HIDDEN / 32; ++kt) {
        const int k0 = kt * 32;
        __syncthreads();
        #pragma unroll
        for (int u = 0; u < 2; ++u) {
            const int s   = (wid * 2 + u) * 64 + lane;
            const int row = s >> 2;
            const int kc  = (s & 3) * 8;
            const int lo  = (wid * 2 + u) * 512;
            const size_t ga = (size_t)(m0 + row) * HIDDEN + k0 + kc;
            const size_t gb = (size_t)(n0 + row) * HIDDEN + k0 + kc;
            gload16(Agh + ga, &LAh[lo]);
            gload16(Agl + ga, &LAl[lo]);
            gload16(Bgh + gb, &LBh[lo]);
            gload16(Bgl + gb, &LBl[lo]);
        }
        __syncthreads();

        short8 ah[4], al[4], bh[4], bl[4];
        #pragma unroll
        for (int i = 0; i < 4; ++i) {
            const int ro = (wr * 64 + i * 16 + l15) * 32 + lg * 8;
            ah[i] = *(const short8*)&LAh[ro];
            al[i] = *(const short8*)&LAl[ro];
        }
        #pragma unroll
        for (int j = 0; j < 4; ++j) {
            const int ro = (wc * 64 + j * 16 + l15) * 32 + lg * 8;
            bh[j] = *(const short8*)&LBh[ro];
            bl[j] = *(const short8*)&LBl[ro];
        }
        #pragma unroll
        for (int i = 0; i < 4; ++i)
            #pragma unroll
            for (int j = 0; j < 4; ++j) {
                acc[i][j] = MFMA16(ah[i], bh[j], acc[i][j]);
                acc[i][j] = MFMA16(ah[i], bl[j], acc[i][j]);
                acc[i][j] = MFMA16(al[i], bh[j], acc[i][j]);
            }
    }

    #pragma unroll
    for (int i = 0; i < 4; ++i) {
        #pragma unroll
        for (int r = 0; r < 4; ++r) {
            const int mr  = m0 + wr * 64 + i * 16 + lg * 4 + r;
            const int inp = (mr >= MROWS) ? 1 : 0;
            const int mm  = mr & (MROWS - 1);
            const int bb  = mm >> 10, ssr = mm & (SS - 1);
            #pragma unroll
            for (int j = 0; j < 4; ++j) {
                const int n   = n0 + wc * 64 + j * 16 + l15;
                const int sel = n / HIDDEN;
                const int hh  = (n % HIDDEN) >> 6;
                const int dd  = n & 63;
                const float v = acc[i][j][r];
                const u16 vh = f2bf(v);
                const u16 vl = f2bf(v - bf2f(vh));
                u16* ph = planes + (size_t)(inp * 6 + sel * 2) * QKV_ELEMS;
                const size_t idx = (((size_t)bb * NH + hh) * SS + ssr) * HD + dd;
                ph[idx] = vh;
                ph[QKV_ELEMS + idx] = vl;
            }
        }
    }
}

// ---------------------------------------------------------------------------
// k3: MFMA flash attention (round-9 validated; unchanged)
// ---------------------------------------------------------------------------
__global__ __launch_bounds__(256)
__attribute__((amdgpu_waves_per_eu(2, 2)))
void attn_mfma_kernel(const u16* __restrict__ planes,
                      u16* __restrict__ o_h, u16* __restrict__ o_l)
{
    __shared__ u16 Khi[64 * 64], Klo[64 * 64];     // [key][d]   8 KB each
    __shared__ u16 Vthi[64 * 64], Vtlo[64 * 64];   // [d][key]   8 KB each
    __shared__ u16 Pbuf[4][2][2][16 * 64];         // [wave][grp][hi/lo] 32 KB

    const int tid  = threadIdx.x;
    const int lane = tid & 63, wid = tid >> 6;
    const int l15  = lane & 15, lg = lane >> 4;

    const int work = (blockIdx.x & 7) * 288 + (blockIdx.x >> 3);
    const int qt   = work & 7;
    const int bh   = (work >> 3) % 96;
    const int aid  = (work >> 3) / 96;

    const int qinp  = (aid == 1) ? 1 : 0;
    const int kvinp = (aid == 0) ? 0 : 1;
    const size_t base = (size_t)bh * SS * HD;

    const u16* __restrict__ qhi = planes + (size_t)(qinp * 6 + 0) * QKV_ELEMS;
    const u16* __restrict__ qlo = qhi + QKV_ELEMS;
    const u16* __restrict__ khi = planes + (size_t)(kvinp * 6 + 2) * QKV_ELEMS;
    const u16* __restrict__ klo = khi + QKV_ELEMS;
    const u16* __restrict__ vhi = planes + (size_t)(kvinp * 6 + 4) * QKV_ELEMS;
    const u16* __restrict__ vlo = vhi + QKV_ELEMS;

    const int qb = qt * 128 + wid * 32;
    short8 qfh[2][2], qfl[2][2];                   // [group][dk]
    #pragma unroll
    for (int g = 0; g < 2; ++g)
        #pragma unroll
        for (int dk = 0; dk < 2; ++dk) {
            const size_t off = base + (size_t)(qb + g * 16 + l15) * HD + dk * 32 + lg * 8;
            qfh[g][dk] = *(const short8*)&qhi[off];
            qfl[g][dk] = *(const short8*)&qlo[off];
        }

    const f32x4 fz = {0.f, 0.f, 0.f, 0.f};
    f32x4 O[2][4] = {{fz, fz, fz, fz}, {fz, fz, fz, fz}};
    float mrun[2] = {-INFINITY, -INFINITY};
    float lrun[2] = {0.f, 0.f};

    for (int kt0 = 0; kt0 < SS; kt0 += 64) {
        __syncthreads();
        {   // ---- stage K (swz) and V transposed (swzV) ----
            #pragma unroll
            for (int i = 0; i < 2; ++i) {
                const int c  = tid + 256 * i;
                const int ky = c >> 3, dg = (c & 7) * 8;
                const size_t g = base + (size_t)(kt0 + ky) * HD + dg;
                const int b = swz(ky, dg * 2);
                *(short8*)((char*)Khi + b) = *(const short8*)&khi[g];
                *(short8*)((char*)Klo + b) = *(const short8*)&klo[g];
            }
            const int kp = tid >> 3;
            const int d0 = (tid & 7) * 8;
            const size_t g0 = base + (size_t)(kt0 + 2 * kp) * HD + d0;
            short8 vah = *(const short8*)&vhi[g0];
            short8 vbh = *(const short8*)&vhi[g0 + HD];
            short8 val = *(const short8*)&vlo[g0];
            short8 vbl = *(const short8*)&vlo[g0 + HD];
            #pragma unroll
            for (int i = 0; i < 8; ++i) {
                const int d = d0 + i;
                const int b = swzV(d, kp * 4);
                *(u32*)((char*)Vthi + b) = (u32)(u16)vah[i] | ((u32)(u16)vbh[i] << 16);
                *(u32*)((char*)Vtlo + b) = (u32)(u16)val[i] | ((u32)(u16)vbl[i] << 16);
            }
        }
        __syncthreads();

        // ---- S^T = K Q ----
        f32x4 S[2][4] = {{fz, fz, fz, fz}, {fz, fz, fz, fz}};
        #pragma unroll
        for (int dk = 0; dk < 2; ++dk) {
            #pragma unroll
            for (int kt = 0; kt < 4; ++kt) {
                const int b = swz(kt * 16 + l15, dk * 64 + lg * 16);
                short8 kfh = *(const short8*)((char*)Khi + b);
                short8 kfl = *(const short8*)((char*)Klo + b);
                #pragma unroll
                for (int g = 0; g < 2; ++g) {
                    S[g][kt] = MFMA16(kfh, qfh[g][dk], S[g][kt]);
                    S[g][kt] = MFMA16(kfl, qfh[g][dk], S[g][kt]);
                    S[g][kt] = MFMA16(kfh, qfl[g][dk], S[g][kt]);
                }
            }
        }

        // ---- per-group softmax (defer-max, THR=8) ----
        #pragma unroll
        for (int g = 0; g < 2; ++g) {
            float pm = -INFINITY;
            #pragma unroll
            for (int kt = 0; kt < 4; ++kt)
                #pragma unroll
                for (int r = 0; r < 4; ++r) {
                    S[g][kt][r] *= ATT_SCALE;
                    pm = fmaxf(pm, S[g][kt][r]);
                }
            pm = fmaxf(pm, __shfl_xor(pm, 16, 64));
            pm = fmaxf(pm, __shfl_xor(pm, 32, 64));

            if (__any(pm - mrun[g] > 8.f)) {       // wave-uniform rescale
                const float mnew = fmaxf(mrun[g], pm);
                const float corr = __expf(mrun[g] - mnew);
                lrun[g] *= corr;
                #pragma unroll
                for (int r = 0; r < 4; ++r) {
                    const float c = __shfl(corr, lg * 4 + r, 64);
                    #pragma unroll
                    for (int dn = 0; dn < 4; ++dn) O[g][dn][r] *= c;
                }
                mrun[g] = mnew;
            }
            const float mref = mrun[g];

            u16* __restrict__ Ph = &Pbuf[wid][g][0][0];
            u16* __restrict__ Pl = &Pbuf[wid][g][1][0];
            float psum = 0.f;
            #pragma unroll
            for (int kt = 0; kt < 4; ++kt) {
                float p0 = __expf(S[g][kt][0] - mref);
                float p1 = __expf(S[g][kt][1] - mref);
                float p2 = __expf(S[g][kt][2] - mref);
                float p3 = __expf(S[g][kt][3] - mref);
                psum += (p0 + p1) + (p2 + p3);
                const u32 u0 = __float_as_uint(p0), u1 = __float_as_uint(p1);
                const u32 u2 = __float_as_uint(p2), u3 = __float_as_uint(p3);
                const u32 hpk0 = (u0 >> 16) | (u1 & 0xFFFF0000u);
                const u32 hpk1 = (u2 >> 16) | (u3 & 0xFFFF0000u);
                const float l0 = p0 - __uint_as_float(u0 & 0xFFFF0000u);
                const float l1 = p1 - __uint_as_float(u1 & 0xFFFF0000u);
                const float l2 = p2 - __uint_as_float(u2 & 0xFFFF0000u);
                const float l3 = p3 - __uint_as_float(u3 & 0xFFFF0000u);
                const u32 lpk0 = (__float_as_uint(l0) >> 16) | (__float_as_uint(l1) & 0xFFFF0000u);
                const u32 lpk1 = (__float_as_uint(l2) >> 16) | (__float_as_uint(l3) & 0xFFFF0000u);
                const int b0 = swz(l15, kt * 32 + lg * 8);
                *(uint2*)((char*)Ph + b0) = make_uint2(hpk0, hpk1);
                *(uint2*)((char*)Pl + b0) = make_uint2(lpk0, lpk1);
            }
            psum += __shfl_xor(psum, 16, 64);
            psum += __shfl_xor(psum, 32, 64);
            lrun[g] += psum;
        }

        // ---- O += P V ----
        #pragma unroll
        for (int ch = 0; ch < 2; ++ch) {
            short8 vfh[4], vfl[4];
            #pragma unroll
            for (int dn = 0; dn < 4; ++dn) {
                const int vb = swzV(dn * 16 + l15, ch * 64 + lg * 16);
                vfh[dn] = *(const short8*)((char*)Vthi + vb);
                vfl[dn] = *(const short8*)((char*)Vtlo + vb);
            }
            #pragma unroll
            for (int g = 0; g < 2; ++g) {
                const int pb = swz(l15, ch * 64 + lg * 16);
                short8 pah = *(const short8*)((char*)&Pbuf[wid][g][0][0] + pb);
                short8 pal = *(const short8*)((char*)&Pbuf[wid][g][1][0] + pb);
                #pragma unroll
                for (int dn = 0; dn < 4; ++dn) {
                    O[g][dn] = MFMA16(pah, vfh[dn], O[g][dn]);
                    O[g][dn] = MFMA16(pah, vfl[dn], O[g][dn]);
                    O[g][dn] = MFMA16(pal, vfh[dn], O[g][dn]);
                }
            }
        }
    }

    // ---- epilogue ----
    const int b = bh / NH, h = bh % NH;
    #pragma unroll
    for (int g = 0; g < 2; ++g) {
        const float linv = 1.f / lrun[g];
        #pragma unroll
        for (int r = 0; r < 4; ++r) {
            const float inv = __shfl(linv, lg * 4 + r, 64);
            const int grow = aid * MROWS + b * SS + qb + g * 16 + lg * 4 + r;
            const size_t rb = (size_t)grow * HIDDEN + h * HD;
            #pragma unroll
            for (int dn = 0; dn < 4; ++dn) {
                const float v = O[g][dn][r] * inv;
                const u16 vh = f2bf(v);
                o_h[rb + dn * 16 + l15] = vh;
                o_l[rb + dn * 16 + l15] = f2bf(v - bf2f(vh));
            }
        }
    }
}

// ---------------------------------------------------------------------------
// k4: MFMA GEMM out, single-buffer (round-8 body; waves_per_eu(2,3))
// ---------------------------------------------------------------------------
__global__ __launch_bounds__(256)
__attribute__((amdgpu_waves_per_eu(2, 3)))
void gemm_out_mfma(const u16* __restrict__ Agh, const u16* __restrict__ Agl,
                   const u16* __restrict__ Bgh, const u16* __restrict__ Bgl,
                   const float* __restrict__ bias, float* __restrict__ out)
{
    __shared__ u16 LAh[4096], LAl[4096], LBh[4096], LBl[4096];

    const int tid = threadIdx.x, lane = tid & 63, wid = tid >> 6;
    const int l15 = lane & 15, lg = lane >> 4;
    const int wr = wid >> 1, wc = wid & 1;
    const int m0 = blockIdx.x * 128, n0 = blockIdx.y * 128;

    const f32x4 fz = {0.f, 0.f, 0.f, 0.f};
    f32x4 acc[4][4] = {{fz,fz,fz,fz},{fz,fz,fz,fz},{fz,fz,fz,fz},{fz,fz,fz,fz}};

    for (int kt = 0; kt < HIDDEN / 32; ++kt) {
        const int k0 = kt * 32;
        __syncthreads();
        #pragma unroll
        for (int u = 0; u < 2; ++u) {
            const int s   = (wid * 2 + u) * 64 + lane;
            const int row = s >> 2;
            const int kc  = (s & 3) * 8;
            const int lo  = (wid * 2 + u) * 512;
            const size_t ga = (size_t)(m0 + row) * HIDDEN + k0 + kc;
            const size_t gb = (size_t)(n0 + row) * HIDDEN + k0 + kc;
            gload16(Agh + ga, &LAh[lo]);
            gload16(Agl + ga, &LAl[lo]);
            gload16(Bgh + gb, &LBh[lo]);
            gload16(Bgl + gb, &LBl[lo]);
        }
        __syncthreads();

        short8 ah[4], al[4], bh[4], bl[4];
        #pragma unroll
        for (int i = 0; i < 4; ++i) {
            const int ro = (wr * 64 + i * 16 + l15) * 32 + lg * 8;
            ah[i] = *(const short8*)&LAh[ro];
            al[i] = *(const short8*)&LAl[ro];
        }
        #pragma unroll
        for (int j = 0; j < 4; ++j) {
            const int ro = (wc * 64 + j * 16 + l15) * 32 + lg * 8;
            bh[j] = *(const short8*)&LBh[ro];
            bl[j] = *(const short8*)&LBl[ro];
        }
        #pragma unroll
        for (int i = 0; i < 4; ++i)
            #pragma unroll
            for (int j = 0; j < 4; ++j) {
                acc[i][j] = MFMA16(ah[i], bh[j], acc[i][j]);
                acc[i][j] = MFMA16(ah[i], bl[j], acc[i][j]);
                acc[i][j] = MFMA16(al[i], bh[j], acc[i][j]);
            }
    }

    #pragma unroll
    for (int i = 0; i < 4; ++i) {
        #pragma unroll
        for (int r = 0; r < 4; ++r) {
            const int mr = m0 + wr * 64 + i * 16 + lg * 4 + r;
            #pragma unroll
            for (int j = 0; j < 4; ++j) {
                const int n = n0 + wc * 64 + j * 16 + l15;
                out[(size_t)mr * HIDDEN + n] = acc[i][j][r] + bias[n];
            }
        }
    }
}

// ---------------------------------------------------------------------------
extern "C" void kernel_launch(void* const* d_in, const int* in_sizes, int n_in,
                              void* d_out, int out_size, void* d_ws, size_t ws_size,
                              hipStream_t stream)
{
    const float* x    = (const float*)d_in[0];
    const float* x2   = (const float*)d_in[1];
    const float* Wqkv = (const float*)d_in[2];
    const float* Wout = (const float*)d_in[3];
    const float* bout = (const float*)d_in[4];
    float* out = (float*)d_out;

    char* wsb = (char*)d_ws;
    u16* planes = (u16*)wsb;
    u16* ax_h  = (u16*)(wsb + OFF2);
    u16* ax_l  = ax_h + AX_ELEMS;
    u16* wqt_h = ax_l + AX_ELEMS;
    u16* wqt_l = wqt_h + WQT_ELEMS;
    u16* o_h   = (u16*)(wsb + OFF2);
    u16* o_l   = o_h + O_ELEMS;
    u16* wot_h = o_l + O_ELEMS;
    u16* wot_l = wot_h + (long)HIDDEN * HIDDEN;

    conv_x_kernel<<<3072, 256, 0, stream>>>(x, x2, ax_h, ax_l);

    dim3 gw(12, 48);
    conv_wt_kernel<<<gw, 256, 0, stream>>>(Wqkv, Wout, wqt_h, wqt_l, wot_h, wot_l);

    dim3 g1(M_QKV / 128, N_QKV / 128);            // 128 x 18
    gemm_qkv_mfma<<<g1, 256, 0, stream>>>(ax_h, ax_l, wqt_h, wqt_l, planes);

    attn_mfma_kernel<<<2304, 256, 0, stream>>>(planes, o_h, o_l);

    dim3 g3(3 * MROWS / 128, HIDDEN / 128);       // 192 x 6
    gemm_out_mfma<<<g3, 256, 0, stream>>>(o_h, o_l, wot_h, wot_l, bout, out);
}